// Round 2
// baseline (931.955 us; speedup 1.0000x reference)
//
#include <hip/hip_runtime.h>
#include <hip/hip_bf16.h>

#define TD 49
#define BD 16
#define ND 64
#define HD 128

typedef float  f32x4  __attribute__((ext_vector_type(4)));
typedef __bf16 bf16x8 __attribute__((ext_vector_type(8)));
typedef __bf16 bf16x4 __attribute__((ext_vector_type(4)));

#define KPAD 136                      // 128 + 8 bf16 pad: 272B rows, 16B aligned, 2-way banks (free)
#define LDS1_BYTES (2*128*KPAD*2)     // A[128][KPAD] + W[128][KPAD] bf16 = 69632 B

#define OUT_H    0
#define OUT_CH   6422528
#define OUT_G    12845056
#define OUT_CG   12945408

__device__ __forceinline__ float sigf(float x) {
    return 1.0f / (1.0f + exp2f(-1.442695041f * x));
}
__device__ __forceinline__ float tanhf_fast(float x) {
    x = fminf(fmaxf(x, -20.f), 20.f);
    float e = exp2f(2.885390082f * x);
    return (e - 1.f) / (e + 1.f);
}

// ---------------------------------------------------------------------------
// Phase 1: pre = [p|h_tb|h|h_ta|h_sb|g_t] x [U|Wt0|Wt1|Wt2|Ws|Zt] + b, gates,
//          c_h_new, h_new.  Grid: t(49) x mtile(8) x htile(8). 256 thr/WG.
// Wave w owns rows [w*32, w*32+32) x (8 gates x 16 cols) -> all 8 gates of an
// output element live in one lane's accumulators (in-register gating).
// ---------------------------------------------------------------------------
__global__ __launch_bounds__(256, 2) void phase1_kernel(
    const float* __restrict__ h,   const float* __restrict__ c_h,
    const float* __restrict__ p,   const float* __restrict__ g_t,
    const float* __restrict__ c_g_t, const float* __restrict__ U,
    const float* __restrict__ Wt,  const float* __restrict__ Ws,
    const float* __restrict__ Zt,  const float* __restrict__ bias,
    float* __restrict__ out)
{
    extern __shared__ char smem[];
    __bf16* Al = (__bf16*)smem;              // [128 rows][KPAD] k-contiguous
    __bf16* Wl = (__bf16*)smem + 128*KPAD;   // [128 cols][KPAD] k-contiguous (transposed)

    const int bid   = blockIdx.x;
    const int t     = bid / 64;
    const int rem   = bid % 64;
    const int mtile = rem >> 3;
    const int htile = rem & 7;
    const int tid   = threadIdx.x;
    const int wv    = tid >> 6;
    const int lane  = tid & 63;
    const int lg    = lane >> 4;
    const int l16   = lane & 15;
    const int h0    = htile * 16;

    const f32x4 vzero = {0.f, 0.f, 0.f, 0.f};
    f32x4 acc[2][8];
#pragma unroll
    for (int i = 0; i < 2; ++i)
#pragma unroll
        for (int g = 0; g < 8; ++g) acc[i][g] = vzero;

    for (int s = 0; s < 6; ++s) {
        if (s == 1 && t == 0)     continue;   // h_tb block is all-zero
        if (s == 3 && t == TD-1)  continue;   // h_ta block is all-zero
        __syncthreads();
        // ---- stage A tile: 128 rows x 128 k, f32 -> bf16 (k-contiguous rows)
#pragma unroll
        for (int j = 0; j < 16; ++j) {
            int fid = j*256 + tid;            // [0,4096) float4 slots
            int r   = fid >> 5;
            int k   = (fid & 31) << 2;
            int R   = mtile*128 + r;
            int b   = R >> 6, n = R & 63;
            int bt  = b*TD + t;
            const float* src = nullptr;
            if (s == 0)      src = p   + ((bt*ND + n) << 7) + k;
            else if (s == 1) src = h   + (((bt-1)*ND + n) << 7) + k;
            else if (s == 2) src = h   + ((bt*ND + n) << 7) + k;
            else if (s == 3) src = h   + (((bt+1)*ND + n) << 7) + k;
            else if (s == 4) src = (n > 0) ? (h + ((bt*ND + n - 1) << 7) + k) : nullptr;
            else             src = g_t + (bt << 7) + k;
            f32x4 v = src ? *(const f32x4*)src : vzero;
            bf16x4 w;
            w[0] = (__bf16)v[0]; w[1] = (__bf16)v[1];
            w[2] = (__bf16)v[2]; w[3] = (__bf16)v[3];
            *(bf16x4*)(Al + r*KPAD + k) = w;
        }
        // ---- stage W tile transposed: cols = 8 gates x 16 h, k = 128
#pragma unroll
        for (int j = 0; j < 16; ++j) {
            int fid = j*256 + tid;            // [0,4096)
            int row = fid >> 2;               // (g,k)
            int g   = row >> 7, k = row & 127;
            int q   = fid & 3;
            int gt  = g*TD + t;
            const float* src;
            if (s == 0)      src = U  + (((gt << 7) + k) << 7);
            else if (s <= 3) src = Wt + ((gt*384 + (s-1)*128 + k) << 7);
            else if (s == 4) src = Ws + (((gt << 7) + k) << 7);
            else             src = Zt + (((gt << 7) + k) << 7);
            f32x4 v = *(const f32x4*)(src + h0 + q*4);
            int cb = g*16 + q*4;
            Wl[(cb+0)*KPAD + k] = (__bf16)v[0];
            Wl[(cb+1)*KPAD + k] = (__bf16)v[1];
            Wl[(cb+2)*KPAD + k] = (__bf16)v[2];
            Wl[(cb+3)*KPAD + k] = (__bf16)v[3];
        }
        __syncthreads();
        // ---- MFMA: K=128 in 4 steps of 32
#pragma unroll
        for (int ks = 0; ks < 4; ++ks) {
            int kb = ks*32 + lg*8;
            bf16x8 a0 = *(const bf16x8*)(Al + (wv*32      + l16)*KPAD + kb);
            bf16x8 a1 = *(const bf16x8*)(Al + (wv*32 + 16 + l16)*KPAD + kb);
#pragma unroll
            for (int g = 0; g < 8; ++g) {
                bf16x8 bf = *(const bf16x8*)(Wl + (g*16 + l16)*KPAD + kb);
                acc[0][g] = __builtin_amdgcn_mfma_f32_16x16x32_bf16(a0, bf, acc[0][g], 0, 0, 0);
                acc[1][g] = __builtin_amdgcn_mfma_f32_16x16x32_bf16(a1, bf, acc[1][g], 0, 0, 0);
            }
        }
    }

    // ---- epilogue: gates + cell update, fully in-register
    const int hcol = h0 + l16;
    float bv[8];
#pragma unroll
    for (int g = 0; g < 8; ++g) bv[g] = bias[(g*TD + t)*HD + hcol];

#pragma unroll
    for (int mt = 0; mt < 2; ++mt) {
#pragma unroll
        for (int r = 0; r < 4; ++r) {
            int R  = mtile*128 + wv*32 + mt*16 + lg*4 + r;
            int b  = R >> 6, n = R & 63;
            int bt = b*TD + t;
            int base = ((bt*ND + n) << 7) + hcol;
            float pre[8];
#pragma unroll
            for (int g = 0; g < 8; ++g) pre[g] = acc[mt][g][r] + bv[g];
            float i_  = sigf(pre[0]);
            float flt = sigf(pre[1]);
            float fft = sigf(pre[2]);
            float frt = sigf(pre[3]);
            float fs  = sigf(pre[4]);
            float gn  = sigf(pre[5]);
            float on  = sigf(pre[6]);
            float cn  = tanhf_fast(pre[7]);
            float ccur = c_h[base];
            float ctb  = (t > 0)     ? c_h[base - ND*HD] : 0.f;
            float cta  = (t < TD-1)  ? c_h[base + ND*HD] : 0.f;
            float csb  = (n > 0)     ? c_h[base - HD]    : 0.f;
            float cg   = c_g_t[(bt << 7) + hcol];
            float cnew = i_*cn + flt*ctb + fft*ccur + frt*cta + fs*csb + gn*cg;
            float hnew = on * tanhf_fast(cnew);
            out[OUT_H  + base] = hnew;
            out[OUT_CH + base] = cnew;
        }
    }
}

// ---------------------------------------------------------------------------
// Phase 2: per (b,t) workgroup.  f_gtf GEMM + bone-mean reduction + tiny dots.
// ---------------------------------------------------------------------------
__global__ __launch_bounds__(256, 2) void phase2_kernel(
    const float* __restrict__ g_t, const float* __restrict__ c_g_t,
    const float* __restrict__ Wg,  const float* __restrict__ Zg,
    const float* __restrict__ bg,  float* __restrict__ out)
{
    __shared__ __bf16 A2[64 * KPAD];     // h_new rows (bf16)
    __shared__ __bf16 Wb[128 * KPAD];    // staging region (dots row-major, then Wg0 transposed)
    __shared__ float  gts[128];
    __shared__ float  hm[128];
    __shared__ float  dots[5][128];      // 0..2: g_t·Zg[j]; 3: hm·Wg1; 4: hm·Wg2
    __shared__ float  ps[2][128];
    __shared__ float  red[4][128];

    const int bid  = blockIdx.x;
    const int t    = bid >> 4;
    const int b    = bid & 15;
    const int tid  = threadIdx.x;
    const int wv   = tid >> 6;
    const int lane = tid & 63;
    const int lg   = lane >> 4;
    const int l16  = lane & 15;
    const int bt   = b*TD + t;

    const float* hn  = out + OUT_H;
    const float* chn = out + OUT_CH;

    // ---- stage h_new -> A2 bf16
#pragma unroll
    for (int j = 0; j < 8; ++j) {
        int fid = j*256 + tid;               // [0,2048): 64 rows x 32 f32x4
        int r   = fid >> 5;
        int k   = (fid & 31) << 2;
        f32x4 v = *(const f32x4*)(hn + ((bt*ND + r) << 7) + k);
        bf16x4 w;
        w[0] = (__bf16)v[0]; w[1] = (__bf16)v[1];
        w[2] = (__bf16)v[2]; w[3] = (__bf16)v[3];
        *(bf16x4*)(A2 + r*KPAD + k) = w;
    }
    if (tid < 128) gts[tid] = g_t[(bt << 7) + tid];
    __syncthreads();

    // ---- column sums -> h_mean
    {
        int c = tid & 127, half = tid >> 7;
        float sum_ = 0.f;
        for (int r2 = 0; r2 < 32; ++r2) sum_ += (float)A2[(half*32 + r2)*KPAD + c];
        ps[half][c] = sum_;
    }
    __syncthreads();
    if (tid < 128) hm[tid] = (ps[0][tid] + ps[1][tid]) * (1.f/64.f);

    // ---- 5 small dot products (vec[128] · M[128][128])
    for (int m = 0; m < 5; ++m) {
        const float* M = (m < 3) ? (Zg + ((m*TD + t) << 14))
                                 : (Wg + (((m-2)*TD + t) << 14));
        const bool use_hm = (m >= 3);
        __syncthreads();
#pragma unroll
        for (int j = 0; j < 16; ++j) {       // stage M row-major [k][c] bf16, stride 128
            int fid = j*256 + tid;           // [0,4096): 128 rows x 32 f32x4  (FIX: was 8 iters)
            int k   = fid >> 5;
            int c4  = (fid & 31) << 2;
            f32x4 v = *(const f32x4*)(M + (k << 7) + c4);
            bf16x4 w;
            w[0] = (__bf16)v[0]; w[1] = (__bf16)v[1];
            w[2] = (__bf16)v[2]; w[3] = (__bf16)v[3];
            *(bf16x4*)(Wb + (k << 7) + c4) = w;
        }
        __syncthreads();
        {
            int c = tid & 127, half = tid >> 7;
            const float* vec = use_hm ? hm : gts;
            float sum_ = 0.f;
            for (int k = half*64; k < half*64 + 64; ++k)
                sum_ += vec[k] * (float)Wb[(k << 7) + c];
            ps[half][c] = sum_;
        }
        __syncthreads();
        if (tid < 128) dots[m][tid] = ps[0][tid] + ps[1][tid];
    }

    // ---- stage Wg0 transposed [c][KPAD] for MFMA
    {
        const float* M = Wg + (t << 14);
        __syncthreads();
#pragma unroll
        for (int j = 0; j < 16; ++j) {
            int fid = j*256 + tid;           // [0,4096)
            int k   = fid >> 5;
            int q   = fid & 31;
            f32x4 v = *(const f32x4*)(M + (k << 7) + q*4);
            int cb = q*4;
            Wb[(cb+0)*KPAD + k] = (__bf16)v[0];
            Wb[(cb+1)*KPAD + k] = (__bf16)v[1];
            Wb[(cb+2)*KPAD + k] = (__bf16)v[2];
            Wb[(cb+3)*KPAD + k] = (__bf16)v[3];
        }
        __syncthreads();
    }

    // ---- MFMA: rows (bones) wv*16..+15, cols 128, K=128
    f32x4 acc[8];
    const f32x4 vzero = {0.f, 0.f, 0.f, 0.f};
#pragma unroll
    for (int cf = 0; cf < 8; ++cf) acc[cf] = vzero;
#pragma unroll
    for (int ks = 0; ks < 4; ++ks) {
        int kb = ks*32 + lg*8;
        bf16x8 a = *(const bf16x8*)(A2 + (wv*16 + l16)*KPAD + kb);
#pragma unroll
        for (int cf = 0; cf < 8; ++cf) {
            bf16x8 bfr = *(const bf16x8*)(Wb + (cf*16 + l16)*KPAD + kb);
            acc[cf] = __builtin_amdgcn_mfma_f32_16x16x32_bf16(a, bfr, acc[cf], 0, 0, 0);
        }
    }

    // ---- epilogue: f_gtf, mean over bones
#pragma unroll
    for (int cf = 0; cf < 8; ++cf) {
        int col = cf*16 + l16;
        float z = dots[0][col] + bg[(0*TD + t)*HD + col];
        float macc = 0.f;
#pragma unroll
        for (int r = 0; r < 4; ++r) {
            int row = wv*16 + lg*4 + r;
            float f  = sigf(acc[cf][r] + z);
            float cv = chn[((bt*ND + row) << 7) + col];
            macc += f * cv;
        }
        macc += __shfl_xor(macc, 16, 64);
        macc += __shfl_xor(macc, 32, 64);
        if (lane < 16) red[wv][col] = macc;
    }
    __syncthreads();
    if (tid < 128) {
        int c = tid;
        float Mn  = (red[0][c] + red[1][c] + red[2][c] + red[3][c]) * (1.f/64.f);
        float g_g = sigf(dots[3][c] + dots[1][c] + bg[(1*TD + t)*HD + c]);
        float o_g = sigf(dots[4][c] + dots[2][c] + bg[(2*TD + t)*HD + c]);
        float cgt = c_g_t[(bt << 7) + c];
        float cgn = Mn + g_g * cgt;
        float gnw = tanhf_fast(cgn) * o_g;
        out[OUT_G  + (bt << 7) + c] = gnw;
        out[OUT_CG + (bt << 7) + c] = cgn;
    }
}

extern "C" void kernel_launch(void* const* d_in, const int* in_sizes, int n_in,
                              void* d_out, int out_size, void* d_ws, size_t ws_size,
                              hipStream_t stream) {
    const float* h     = (const float*)d_in[0];
    const float* c_h   = (const float*)d_in[1];
    const float* p     = (const float*)d_in[2];
    const float* g_t   = (const float*)d_in[3];
    const float* c_g_t = (const float*)d_in[4];
    const float* U     = (const float*)d_in[5];
    const float* Wt    = (const float*)d_in[6];
    const float* Ws    = (const float*)d_in[7];
    const float* Zt    = (const float*)d_in[8];
    const float* b     = (const float*)d_in[9];
    const float* Wg    = (const float*)d_in[10];
    const float* Zg    = (const float*)d_in[11];
    const float* bg    = (const float*)d_in[12];
    float* out = (float*)d_out;

    (void)hipFuncSetAttribute(reinterpret_cast<const void*>(phase1_kernel),
                              hipFuncAttributeMaxDynamicSharedMemorySize, LDS1_BYTES);
    phase1_kernel<<<TD*64, 256, LDS1_BYTES, stream>>>(h, c_h, p, g_t, c_g_t,
                                                      U, Wt, Ws, Zt, b, out);
    phase2_kernel<<<TD*BD, 256, 0, stream>>>(g_t, c_g_t, Wg, Zg, bg, out);
}

// Round 3
// 257.832 us; speedup vs baseline: 3.6146x; 3.6146x over previous
//
#include <hip/hip_runtime.h>
#include <hip/hip_bf16.h>

#define TD 49
#define BD 16
#define ND 64
#define HD 128

typedef float  f32x4  __attribute__((ext_vector_type(4)));
typedef __bf16 bf16x8 __attribute__((ext_vector_type(8)));
typedef __bf16 bf16x4 __attribute__((ext_vector_type(4)));

// ---------------- workspace layout (bf16 element offsets) ----------------
#define WP_OFF   0u
#define WP_ELEMS 38535168u           // 49*8*128*768  : W' [t][g][h][k] bf16
#define HB_OFF   38535168u           // h  bf16 [B,T,N,H]
#define ACT_ELEMS 6422528u           // 16*49*64*128
#define PB_OFF   44957696u           // p  bf16
#define GB_OFF   51380224u           // g_t bf16 [B,T,H]
#define GT_ELEMS 100352u
#define ZP_OFF   51480576u           // 2048 bf16 zeros (pad source page)
// total = 51482624 elems = 102,965,248 bytes

#define OUT_H    0
#define OUT_CH   6422528
#define OUT_G    12845056
#define OUT_CG   12945408

#define KPAD 136
#define LDS1_BYTES 131072            // A[2][256][64] + B[2][256][64] bf16

__device__ __forceinline__ float sigf(float x) {
    return 1.0f / (1.0f + exp2f(-1.442695041f * x));
}
__device__ __forceinline__ float tanhf_fast(float x) {
    x = fminf(fmaxf(x, -20.f), 20.f);
    float e = exp2f(2.885390082f * x);
    return (e - 1.f) / (e + 1.f);
}
__device__ __forceinline__ void gload16(const void* g, void* l) {
    __builtin_amdgcn_global_load_lds((const __attribute__((address_space(1))) void*)g,
                                     (__attribute__((address_space(3))) void*)l, 16, 0, 0);
}

// ---------------------------------------------------------------------------
// prep_acts: cast h, p, g_t f32 -> bf16 into ws; fill zero page.
// ---------------------------------------------------------------------------
__global__ void prep_acts(const float* __restrict__ h, const float* __restrict__ p,
                          const float* __restrict__ g, __bf16* __restrict__ ws)
{
    unsigned i = blockIdx.x * 256u + threadIdx.x;
    const unsigned HU = ACT_ELEMS / 4u, GU = GT_ELEMS / 4u;
    const float* src;
    unsigned dst;
    if (i < HU)                 { src = h + (size_t)i * 4;          dst = HB_OFF + i * 4; }
    else if (i < 2u*HU)         { unsigned j = i - HU;   src = p + (size_t)j * 4; dst = PB_OFF + j * 4; }
    else if (i < 2u*HU + GU)    { unsigned j = i - 2u*HU; src = g + (size_t)j * 4; dst = GB_OFF + j * 4; }
    else if (i < 2u*HU + GU + 512u) {
        unsigned j = i - 2u*HU - GU;
        bf16x4 z = {};
        *(bf16x4*)(ws + ZP_OFF + j * 4) = z;
        return;
    } else return;
    f32x4 v = *(const f32x4*)src;
    bf16x4 w;
    w[0] = (__bf16)v[0]; w[1] = (__bf16)v[1]; w[2] = (__bf16)v[2]; w[3] = (__bf16)v[3];
    *(bf16x4*)(ws + dst) = w;
}

// ---------------------------------------------------------------------------
// prep_w: transpose+cast weights into W'[t][g][h=128][k=768] bf16,
//         k-order = [U | Wt0 | Wt1 | Wt2 | Ws | Zt].
// grid = 49*8*12 (one 64-k chunk per block).
// ---------------------------------------------------------------------------
__global__ __launch_bounds__(256) void prep_w(
    const float* __restrict__ U, const float* __restrict__ Wt,
    const float* __restrict__ Ws, const float* __restrict__ Zt,
    __bf16* __restrict__ wp)
{
    __shared__ __bf16 tile[64 * 132];
    int bid = blockIdx.x;
    int tg  = bid / 12;              // t*8+g
    int c   = bid % 12;
    int t   = tg >> 3, g = tg & 7;
    int gt  = g * TD + t;
    int tid = threadIdx.x;
    int k0  = c * 64;

#pragma unroll
    for (int u = 0; u < 8; ++u) {
        int unit = u * 256 + tid;    // [0,2048): 64 k x 32 f32x4
        int kk = unit >> 5;
        int h4 = (unit & 31) << 2;
        int k  = k0 + kk;
        const float* src;
        if (k < 128)      src = U  + ((size_t)(gt * 128 + k)       << 7);
        else if (k < 512) src = Wt + ((size_t)(gt * 384 + (k-128)) << 7);
        else if (k < 640) src = Ws + ((size_t)(gt * 128 + (k-512)) << 7);
        else              src = Zt + ((size_t)(gt * 128 + (k-640)) << 7);
        f32x4 v = *(const f32x4*)(src + h4);
        bf16x4 w;
        w[0] = (__bf16)v[0]; w[1] = (__bf16)v[1]; w[2] = (__bf16)v[2]; w[3] = (__bf16)v[3];
        *(bf16x4*)(tile + kk * 132 + h4) = w;
    }
    __syncthreads();
#pragma unroll
    for (int u = 0; u < 2; ++u) {
        int unit = u * 256 + tid;    // [0,512): 128 h x 4 k-groups
        int hh = unit >> 2;
        int kg = unit & 3;
        bf16x8 v0, v1;
#pragma unroll
        for (int j = 0; j < 8; ++j) v0[j] = tile[(kg * 16 + j) * 132 + hh];
#pragma unroll
        for (int j = 0; j < 8; ++j) v1[j] = tile[(kg * 16 + 8 + j) * 132 + hh];
        __bf16* dst = wp + (size_t)(tg * 128 + hh) * 768 + k0 + kg * 16;
        *(bf16x8*)dst       = v0;
        *(bf16x8*)(dst + 8) = v1;
    }
}

// ---------------------------------------------------------------------------
// Phase 1: 256x256-tile GEMM over K=768 + fused gates.
// grid = 49 t x 4 mtile x 4 ntile (XCD-swizzled). 512 thr = 8 waves (4M x 2H).
// N=256 = 8 gates x 32 hcols; wave (wm,wh) owns M 64 rows x 16 hcols x 8 gates.
// LDS tiles [256][64] bf16, XOR-swizzled (byte ^= (row&7)<<4) via pre-swizzled
// global_load_lds sources; double-buffered, 2-phase pipeline.
// ---------------------------------------------------------------------------
__global__ __launch_bounds__(512, 1) void phase1_kernel(
    const __bf16* __restrict__ ws,
    const float* __restrict__ c_h, const float* __restrict__ c_g_t,
    const float* __restrict__ bias, float* __restrict__ out)
{
    extern __shared__ __bf16 smem[];      // A: [0,32768) elems, B: [32768,65536)
    const __bf16* hb = ws + HB_OFF;
    const __bf16* pb = ws + PB_OFF;
    const __bf16* gb = ws + GB_OFF;
    const __bf16* wp = ws + WP_OFF;
    const __bf16* zp = ws + ZP_OFF;

    int bid = blockIdx.x;
    int swz = (bid & 7) * 98 + (bid >> 3);   // XCD swizzle, bijective (784 = 8*98)
    int t     = swz >> 4;
    int rem   = swz & 15;
    int mtile = rem >> 2, ntile = rem & 3;

    int tid  = threadIdx.x;
    int wave = tid >> 6, lane = tid & 63;
    int wm = wave >> 1, wh = wave & 1;
    int lg = lane >> 4, l16 = lane & 15;

    // staging per-lane constants: chunk = wave + it*8 covers rows R0 + it*64
    const int R0   = (wave << 3) + (lane >> 3);        // n in [0,64)
    const int k16s = ((lane & 7) ^ (R0 & 7)) << 3;     // pre-swizzled k elem off
    const int n    = R0;

    f32x4 acc[4][8];
    const f32x4 vzero = {0.f, 0.f, 0.f, 0.f};
#pragma unroll
    for (int mi = 0; mi < 4; ++mi)
#pragma unroll
        for (int g = 0; g < 8; ++g) acc[mi][g] = vzero;

    // fragment read bases (byte offsets into a buffer)
    int rbA[4], rsA[4], rbB[8], rsB[8];
#pragma unroll
    for (int mi = 0; mi < 4; ++mi) {
        int row = wm * 64 + mi * 16 + l16;
        rbA[mi] = row << 7;
        rsA[mi] = (row & 7) << 4;
    }
#pragma unroll
    for (int g = 0; g < 8; ++g) {
        int row = g * 32 + wh * 16 + l16;
        rbB[g] = row << 7;
        rsB[g] = (row & 7) << 4;
    }
    const int kb0 = lg << 4;

#define STAGE_A(BUF, KS) do {                                                   \
        int s_   = (KS) >> 1;                                                   \
        int koff = (((KS) & 1) << 6) + k16s;                                    \
        _Pragma("unroll")                                                       \
        for (int it = 0; it < 4; ++it) {                                        \
            int b_  = mtile * 4 + it;                                           \
            int bt_ = b_ * TD + t;                                              \
            const __bf16* src;                                                  \
            if (s_ == 0)      src = pb + ((bt_ * ND + n) << 7) + koff;          \
            else if (s_ == 1) src = (t > 0)    ? hb + (((bt_-1) * ND + n) << 7) + koff : zp; \
            else if (s_ == 2) src = hb + ((bt_ * ND + n) << 7) + koff;          \
            else if (s_ == 3) src = (t < TD-1) ? hb + (((bt_+1) * ND + n) << 7) + koff : zp; \
            else if (s_ == 4) src = (n > 0)    ? hb + ((bt_ * ND + n - 1) << 7) + koff : zp; \
            else              src = gb + (bt_ << 7) + koff;                     \
            __bf16* dst = smem + (BUF) * 16384 + (wave + it * 8) * 512;         \
            gload16(src, dst);                                                  \
        }                                                                       \
    } while (0)

#define STAGE_B(BUF, KS) do {                                                   \
        _Pragma("unroll")                                                       \
        for (int it = 0; it < 4; ++it) {                                        \
            int np = R0 + it * 64;                                              \
            int g_ = np >> 5, hc = np & 31;                                     \
            const __bf16* src = wp + (size_t)((t * 8 + g_) * 128 + ntile * 32 + hc) * 768 \
                                   + ((KS) << 6) + k16s;                        \
            __bf16* dst = smem + 32768 + (BUF) * 16384 + (wave + it * 8) * 512; \
            gload16(src, dst);                                                  \
        }                                                                       \
    } while (0)

    STAGE_A(0, 0);
    STAGE_B(0, 0);
    __syncthreads();

    int buf = 0;
    for (int ks = 0; ks < 12; ++ks) {
        if (ks < 11) {
            STAGE_A(buf ^ 1, ks + 1);
            STAGE_B(buf ^ 1, ks + 1);
        }
        const char* Ab = (const char*)(smem + buf * 16384);
        const char* Bb = (const char*)(smem + 32768 + buf * 16384);
#pragma unroll
        for (int ks32 = 0; ks32 < 2; ++ks32) {
            bf16x8 af[4], bfr[8];
#pragma unroll
            for (int mi = 0; mi < 4; ++mi)
                af[mi] = *(const bf16x8*)(Ab + rbA[mi] + (((ks32 << 6) + kb0) ^ rsA[mi]));
#pragma unroll
            for (int g = 0; g < 8; ++g)
                bfr[g] = *(const bf16x8*)(Bb + rbB[g] + (((ks32 << 6) + kb0) ^ rsB[g]));
#pragma unroll
            for (int mi = 0; mi < 4; ++mi)
#pragma unroll
                for (int g = 0; g < 8; ++g)
                    acc[mi][g] = __builtin_amdgcn_mfma_f32_16x16x32_bf16(af[mi], bfr[g], acc[mi][g], 0, 0, 0);
        }
        __syncthreads();
        buf ^= 1;
    }

    // ---- epilogue: gates + cell update, in-register (8 gates per lane) ----
    const int hcol = ntile * 32 + wh * 16 + l16;
    float bv[8];
#pragma unroll
    for (int g = 0; g < 8; ++g) bv[g] = bias[(g * TD + t) * HD + hcol];

#pragma unroll
    for (int mi = 0; mi < 4; ++mi) {
#pragma unroll
        for (int r = 0; r < 4; ++r) {
            int RG = mtile * 256 + wm * 64 + mi * 16 + lg * 4 + r;
            int b  = RG >> 6, nn = RG & 63;
            int bt = b * TD + t;
            int base = ((bt * ND + nn) << 7) + hcol;
            float pre[8];
#pragma unroll
            for (int g = 0; g < 8; ++g) pre[g] = acc[mi][g][r] + bv[g];
            float i_  = sigf(pre[0]);
            float flt = sigf(pre[1]);
            float fft = sigf(pre[2]);
            float frt = sigf(pre[3]);
            float fs  = sigf(pre[4]);
            float gn  = sigf(pre[5]);
            float on  = sigf(pre[6]);
            float cn  = tanhf_fast(pre[7]);
            float ccur = c_h[base];
            float ctb  = (t > 0)      ? c_h[base - ND * HD] : 0.f;
            float cta  = (t < TD - 1) ? c_h[base + ND * HD] : 0.f;
            float csb  = (nn > 0)     ? c_h[base - HD]      : 0.f;
            float cg   = c_g_t[(bt << 7) + hcol];
            float cnew = i_ * cn + flt * ctb + fft * ccur + frt * cta + fs * csb + gn * cg;
            float hnew = on * tanhf_fast(cnew);
            out[OUT_H  + base] = hnew;
            out[OUT_CH + base] = cnew;
        }
    }
#undef STAGE_A
#undef STAGE_B
}

// ---------------------------------------------------------------------------
// Phase 2: per (b,t) workgroup.  f_gtf GEMM + bone-mean reduction + tiny dots.
// ---------------------------------------------------------------------------
__global__ __launch_bounds__(256, 2) void phase2_kernel(
    const float* __restrict__ g_t, const float* __restrict__ c_g_t,
    const float* __restrict__ Wg,  const float* __restrict__ Zg,
    const float* __restrict__ bg,  float* __restrict__ out)
{
    __shared__ __bf16 A2[64 * KPAD];
    __shared__ __bf16 Wb[128 * KPAD];
    __shared__ float  gts[128];
    __shared__ float  hm[128];
    __shared__ float  dots[5][128];
    __shared__ float  ps[2][128];
    __shared__ float  red[4][128];

    const int bid  = blockIdx.x;
    const int t    = bid >> 4;
    const int b    = bid & 15;
    const int tid  = threadIdx.x;
    const int wv   = tid >> 6;
    const int lane = tid & 63;
    const int lg   = lane >> 4;
    const int l16  = lane & 15;
    const int bt   = b * TD + t;

    const float* hn  = out + OUT_H;
    const float* chn = out + OUT_CH;

#pragma unroll
    for (int j = 0; j < 8; ++j) {
        int fid = j * 256 + tid;
        int r   = fid >> 5;
        int k   = (fid & 31) << 2;
        f32x4 v = *(const f32x4*)(hn + ((bt * ND + r) << 7) + k);
        bf16x4 w;
        w[0] = (__bf16)v[0]; w[1] = (__bf16)v[1]; w[2] = (__bf16)v[2]; w[3] = (__bf16)v[3];
        *(bf16x4*)(A2 + r * KPAD + k) = w;
    }
    if (tid < 128) gts[tid] = g_t[(bt << 7) + tid];
    __syncthreads();

    {
        int c = tid & 127, half = tid >> 7;
        float sum_ = 0.f;
        for (int r2 = 0; r2 < 32; ++r2) sum_ += (float)A2[(half * 32 + r2) * KPAD + c];
        ps[half][c] = sum_;
    }
    __syncthreads();
    if (tid < 128) hm[tid] = (ps[0][tid] + ps[1][tid]) * (1.f / 64.f);

    for (int m = 0; m < 5; ++m) {
        const float* M = (m < 3) ? (Zg + ((size_t)(m * TD + t) << 14))
                                 : (Wg + ((size_t)((m - 2) * TD + t) << 14));
        const bool use_hm = (m >= 3);
        __syncthreads();
#pragma unroll
        for (int j = 0; j < 16; ++j) {
            int fid = j * 256 + tid;
            int k   = fid >> 5;
            int c4  = (fid & 31) << 2;
            f32x4 v = *(const f32x4*)(M + (k << 7) + c4);
            bf16x4 w;
            w[0] = (__bf16)v[0]; w[1] = (__bf16)v[1]; w[2] = (__bf16)v[2]; w[3] = (__bf16)v[3];
            *(bf16x4*)(Wb + (k << 7) + c4) = w;
        }
        __syncthreads();
        {
            int c = tid & 127, half = tid >> 7;
            const float* vec = use_hm ? hm : gts;
            float sum_ = 0.f;
            for (int k = half * 64; k < half * 64 + 64; ++k)
                sum_ += vec[k] * (float)Wb[(k << 7) + c];
            ps[half][c] = sum_;
        }
        __syncthreads();
        if (tid < 128) dots[m][tid] = ps[0][tid] + ps[1][tid];
    }

    {
        const float* M = Wg + ((size_t)t << 14);
        __syncthreads();
#pragma unroll
        for (int j = 0; j < 16; ++j) {
            int fid = j * 256 + tid;
            int k   = fid >> 5;
            int q   = fid & 31;
            f32x4 v = *(const f32x4*)(M + (k << 7) + q * 4);
            int cb = q * 4;
            Wb[(cb + 0) * KPAD + k] = (__bf16)v[0];
            Wb[(cb + 1) * KPAD + k] = (__bf16)v[1];
            Wb[(cb + 2) * KPAD + k] = (__bf16)v[2];
            Wb[(cb + 3) * KPAD + k] = (__bf16)v[3];
        }
        __syncthreads();
    }

    f32x4 acc[8];
    const f32x4 vzero = {0.f, 0.f, 0.f, 0.f};
#pragma unroll
    for (int cf = 0; cf < 8; ++cf) acc[cf] = vzero;
#pragma unroll
    for (int ks = 0; ks < 4; ++ks) {
        int kb = ks * 32 + lg * 8;
        bf16x8 a = *(const bf16x8*)(A2 + (wv * 16 + l16) * KPAD + kb);
#pragma unroll
        for (int cf = 0; cf < 8; ++cf) {
            bf16x8 bfr = *(const bf16x8*)(Wb + (cf * 16 + l16) * KPAD + kb);
            acc[cf] = __builtin_amdgcn_mfma_f32_16x16x32_bf16(a, bfr, acc[cf], 0, 0, 0);
        }
    }

#pragma unroll
    for (int cf = 0; cf < 8; ++cf) {
        int col = cf * 16 + l16;
        float z = dots[0][col] + bg[(0 * TD + t) * HD + col];
        float macc = 0.f;
#pragma unroll
        for (int r = 0; r < 4; ++r) {
            int row = wv * 16 + lg * 4 + r;
            float f  = sigf(acc[cf][r] + z);
            float cv = chn[((bt * ND + row) << 7) + col];
            macc += f * cv;
        }
        macc += __shfl_xor(macc, 16, 64);
        macc += __shfl_xor(macc, 32, 64);
        if (lane < 16) red[wv][col] = macc;
    }
    __syncthreads();
    if (tid < 128) {
        int c = tid;
        float Mn  = (red[0][c] + red[1][c] + red[2][c] + red[3][c]) * (1.f / 64.f);
        float g_g = sigf(dots[3][c] + dots[1][c] + bg[(1 * TD + t) * HD + c]);
        float o_g = sigf(dots[4][c] + dots[2][c] + bg[(2 * TD + t) * HD + c]);
        float cgt = c_g_t[(bt << 7) + c];
        float cgn = Mn + g_g * cgt;
        float gnw = tanhf_fast(cgn) * o_g;
        out[OUT_G  + (bt << 7) + c] = gnw;
        out[OUT_CG + (bt << 7) + c] = cgn;
    }
}

extern "C" void kernel_launch(void* const* d_in, const int* in_sizes, int n_in,
                              void* d_out, int out_size, void* d_ws, size_t ws_size,
                              hipStream_t stream) {
    const float* h     = (const float*)d_in[0];
    const float* c_h   = (const float*)d_in[1];
    const float* p     = (const float*)d_in[2];
    const float* g_t   = (const float*)d_in[3];
    const float* c_g_t = (const float*)d_in[4];
    const float* U     = (const float*)d_in[5];
    const float* Wt    = (const float*)d_in[6];
    const float* Ws    = (const float*)d_in[7];
    const float* Zt    = (const float*)d_in[8];
    const float* b     = (const float*)d_in[9];
    const float* Wg    = (const float*)d_in[10];
    const float* Zg    = (const float*)d_in[11];
    const float* bg    = (const float*)d_in[12];
    float* out = (float*)d_out;
    __bf16* ws = (__bf16*)d_ws;

    // prep: 2*1605632 + 25088 + 512 = 3,236,864 units -> 12644 blocks
    prep_acts<<<12644, 256, 0, stream>>>(h, p, g_t, ws);
    prep_w<<<TD * 8 * 12, 256, 0, stream>>>(U, Wt, Ws, Zt, ws + WP_OFF);

    (void)hipFuncSetAttribute(reinterpret_cast<const void*>(phase1_kernel),
                              hipFuncAttributeMaxDynamicSharedMemorySize, LDS1_BYTES);
    phase1_kernel<<<TD * 16, 512, LDS1_BYTES, stream>>>(ws, c_h, c_g_t, b, out);
    phase2_kernel<<<TD * BD, 256, 0, stream>>>(g_t, c_g_t, Wg, Zg, bg, out);
}